// Round 7
// baseline (61.197 us; speedup 1.0000x reference)
//
#include <hip/hip_runtime.h>

// Deformable Conv1d via implicit GEMM on MFMA (bf16 in, fp32 acc).
// out[b,o,t] = sum_{ck} w[o][ck] * xs[b][ck][t],  ck = c*3+k,
// xs[ck][t] = mask[b,k,t] * (G0*x[b,c,U] + G1*x[b,c,U+1])  (constrained sampling)
// R7: TT=32 / 128-thread blocks / 2048 blocks -> 6 blocks/CU (26 KB LDS),
//     direct acc stores (no obuf phase), R5's clean scalar-gather xs-build.
//     Lessons: R2-R5 scratch spill; R6 VALU cut w/ flat time => latency-bound.
#define BB 16
#define CI 128
#define CO 128
#define LL 4096
#define LOUT 4094
#define CK 384           // CI*3 = GEMM K
#define TT 32            // t-tile per block (GEMM N)
#define NTILE 128        // 128*32 = 4096 >= 4094

typedef short short8 __attribute__((ext_vector_type(8)));
typedef float floatx4 __attribute__((ext_vector_type(4)));

__device__ __forceinline__ ushort f2bf(float f) {   // RNE f32 -> bf16
    union { float f; uint u; } v; v.f = f;
    uint r = v.u + 0x7FFFu + ((v.u >> 16) & 1u);
    return (ushort)(r >> 16);
}

// ---- kernel A: w f32 -> bf16 into d_ws (49152 elems, 8/thread) ----
__global__ __launch_bounds__(256)
void wcvt_kernel(const float* __restrict__ w, ushort* __restrict__ wbf) {
    const int i = (blockIdx.x * 256 + threadIdx.x) * 8;
    floatx4 a = *(const floatx4*)(w + i);
    floatx4 b = *(const floatx4*)(w + i + 4);
    uint4 q;
    q.x = (uint)f2bf(a[0]) | ((uint)f2bf(a[1]) << 16);
    q.y = (uint)f2bf(a[2]) | ((uint)f2bf(a[3]) << 16);
    q.z = (uint)f2bf(b[0]) | ((uint)f2bf(b[1]) << 16);
    q.w = (uint)f2bf(b[2]) | ((uint)f2bf(b[3]) << 16);
    *(uint4*)(wbf + i) = q;
}

__global__ __launch_bounds__(128, 3)
void dconv1d_mfma_kernel(const float* __restrict__ x,
                         const float* __restrict__ offs,
                         const float* __restrict__ mask,
                         const ushort* __restrict__ wbf,
                         const float* __restrict__ bias,
                         float* __restrict__ out) {
    // xs tile: [t][ck] bf16, XOR-swizzled cols: col' = col ^ ((t&15)<<3). 24 KB.
    __shared__ ushort xs[TT][CK];

    const int tid  = threadIdx.x;
    const int lane = tid & 63;
    const int wv   = tid >> 6;          // wave 0..1 -> o-rows [wv*64, wv*64+64)
    const int bid  = blockIdx.x;
    // XCD-chunked swizzle over 2048 blocks: XCD k (= bid%8) owns lb in
    // [k*256,(k+1)*256) = b in {2k,2k+1}, all 128 t-tiles. Bijective.
    const int lb   = (bid & 7) * 256 + (bid >> 3);
    const int b    = lb >> 7;
    const int t0   = (lb & 127) * TT;

    // ---- build xs tile: unit = (t, c-group of 8). 512 units / 128 threads. ----
    for (int it = 0; it < 4; ++it) {
        const int u  = tid + it * 128;
        const int t  = u & (TT - 1);
        const int cg = u >> 5;                 // 0..15
        const int gt = t0 + t;

        float g0[3], g1[3];
        int   U[3];
#pragma unroll
        for (int k = 0; k < 3; ++k) {
            float ofv = 0.f, mv = 0.f;
            if (gt < LOUT) {
                ofv = offs[((size_t)b * LOUT + gt) * 3 + k];
                mv  = mask[((size_t)b * 3 + k) * LOUT + gt];
            }
            const float gtf = (float)gt;
            float T = (gtf + (float)k) + ofv;          // exact ref op order
            T = fminf(fmaxf(T, gtf), gtf + 2.0f);      // clamp to receptive field
            int Ui = (int)floorf(T);
            if (Ui > LL - 2) Ui = LL - 2;
            const float Uf = (float)Ui;
            g0[k] = fmaxf(0.f, 1.f - fabsf(Uf - T)) * mv;
            g1[k] = fmaxf(0.f, 1.f - fabsf(Uf + 1.f - T)) * mv;
            U[k] = Ui;
        }

        ushort vals[24];
#pragma unroll
        for (int ci = 0; ci < 8; ++ci) {
            const float* xr = x + ((size_t)b * CI + cg * 8 + ci) * LL;
#pragma unroll
            for (int k = 0; k < 3; ++k) {
                const float x0 = xr[U[k]];
                const float x1 = xr[U[k] + 1];         // U <= LL-2 -> in bounds
                vals[ci * 3 + k] = f2bf(g0[k] * x0 + g1[k] * x1);
            }
        }
        uint dw[12];
#pragma unroll
        for (int j = 0; j < 12; ++j)
            dw[j] = (uint)vals[2 * j] | ((uint)vals[2 * j + 1] << 16);
        const int swz = (t & 15) << 3;
#pragma unroll
        for (int j = 0; j < 3; ++j) {
            const int col = (cg * 24 + j * 8) ^ swz;   // 8-aligned, bijective
            uint4 q; q.x = dw[4*j]; q.y = dw[4*j+1]; q.z = dw[4*j+2]; q.w = dw[4*j+3];
            *(uint4*)(&xs[t][col]) = q;
        }
    }
    __syncthreads();

    // ---- GEMM: 12 k-steps of 32; wave owns 64 o-rows x 32 t ----
    floatx4 zero4 = {0.f, 0.f, 0.f, 0.f};
    floatx4 acc[4][2];
#pragma unroll
    for (int mf = 0; mf < 4; ++mf)
#pragma unroll
        for (int nf = 0; nf < 2; ++nf) acc[mf][nf] = zero4;

    const int arow = wv * 64 + (lane & 15);    // A row = lane&15
    const int ack  = (lane >> 4) * 8;          // A k  = (lane>>4)*8 + j
    const int bswz = (lane & 15) << 3;

#pragma unroll 2
    for (int ks = 0; ks < 12; ++ks) {
        short8 afr[4];
#pragma unroll
        for (int mf = 0; mf < 4; ++mf)
            afr[mf] = *(const short8*)(wbf + (size_t)(arow + mf * 16) * CK + ks * 32 + ack);
        short8 bfr[2];
#pragma unroll
        for (int nf = 0; nf < 2; ++nf) {
            const int tb  = nf * 16 + (lane & 15);     // B col = lane&15
            const int col = (ks * 32 + (lane >> 4) * 8) ^ bswz;
            bfr[nf] = *(const short8*)(&xs[tb][col]);
        }
#pragma unroll
        for (int mf = 0; mf < 4; ++mf)
#pragma unroll
            for (int nf = 0; nf < 2; ++nf)
                acc[mf][nf] = __builtin_amdgcn_mfma_f32_16x16x32_bf16(
                    afr[mf], bfr[nf], acc[mf][nf], 0, 0, 0);
    }

    // ---- epilogue: direct stores. D: col(t)=lane&15, row(o)=(lane>>4)*4+r.
    // Each (mf,r) instruction writes 4 rows x 64B contiguous segments. ----
#pragma unroll
    for (int mf = 0; mf < 4; ++mf) {
#pragma unroll
        for (int r = 0; r < 4; ++r) {
            const int o  = wv * 64 + mf * 16 + (lane >> 4) * 4 + r;
            const float bv = bias[o];
            float* orow = out + ((size_t)b * CO + o) * LOUT;
#pragma unroll
            for (int nf = 0; nf < 2; ++nf) {
                const int gt = t0 + nf * 16 + (lane & 15);
                if (gt < LOUT) orow[gt] = acc[mf][nf][r] + bv;
            }
        }
    }
}

extern "C" void kernel_launch(void* const* d_in, const int* in_sizes, int n_in,
                              void* d_out, int out_size, void* d_ws, size_t ws_size,
                              hipStream_t stream) {
    const float* x    = (const float*)d_in[0];
    const float* offs = (const float*)d_in[1];
    const float* mask = (const float*)d_in[2];
    const float* w    = (const float*)d_in[3];
    const float* bias = (const float*)d_in[4];
    float* out = (float*)d_out;
    ushort* wbf = (ushort*)d_ws;             // 98.3 KB of scratch

    wcvt_kernel<<<dim3(CO * CI * 3 / (256 * 8)), dim3(256), 0, stream>>>(w, wbf);
    dim3 grid(BB * NTILE);   // 2048 blocks
    dim3 block(128);
    dconv1d_mfma_kernel<<<grid, block, 0, stream>>>(x, offs, mask, wbf, bias, out);
}

// Round 8
// 50.564 us; speedup vs baseline: 1.2103x; 1.2103x over previous
//
#include <hip/hip_runtime.h>

// Deformable Conv1d via implicit GEMM on MFMA (bf16 in, fp32 acc).
// out[b,o,t] = sum_{ck} w[o][ck] * xs[b][ck][t],  ck = c*3+k,
// xs[ck][t] = mask[b,k,t] * (G0*x[b,c,U] + G1*x[b,c,U+1])  (constrained sampling)
// R8: TT=32 with 256-thread blocks -> 24 KB LDS -> 6 blocks/CU x 4 waves
//     = 24 waves/CU (2x R5-R7's 12). R7's mistake: 128-thr blocks kept 12.
//     Direct stores (R7 proved clean), mf=2 per-wave shape (R5's).
#define BB 16
#define CI 128
#define CO 128
#define LL 4096
#define LOUT 4094
#define CK 384           // CI*3 = GEMM K
#define TT 32            // t-tile per block (GEMM N)
#define NTILE 128        // 128*32 = 4096 >= 4094

typedef short short8 __attribute__((ext_vector_type(8)));
typedef float floatx4 __attribute__((ext_vector_type(4)));

__device__ __forceinline__ ushort f2bf(float f) {   // RNE f32 -> bf16
    union { float f; uint u; } v; v.f = f;
    uint r = v.u + 0x7FFFu + ((v.u >> 16) & 1u);
    return (ushort)(r >> 16);
}

// ---- kernel A: w f32 -> bf16 into d_ws (49152 elems, 8/thread) ----
__global__ __launch_bounds__(256)
void wcvt_kernel(const float* __restrict__ w, ushort* __restrict__ wbf) {
    const int i = (blockIdx.x * 256 + threadIdx.x) * 8;
    floatx4 a = *(const floatx4*)(w + i);
    floatx4 b = *(const floatx4*)(w + i + 4);
    uint4 q;
    q.x = (uint)f2bf(a[0]) | ((uint)f2bf(a[1]) << 16);
    q.y = (uint)f2bf(a[2]) | ((uint)f2bf(a[3]) << 16);
    q.z = (uint)f2bf(b[0]) | ((uint)f2bf(b[1]) << 16);
    q.w = (uint)f2bf(b[2]) | ((uint)f2bf(b[3]) << 16);
    *(uint4*)(wbf + i) = q;
}

__global__ __launch_bounds__(256, 6)
void dconv1d_mfma_kernel(const float* __restrict__ x,
                         const float* __restrict__ offs,
                         const float* __restrict__ mask,
                         const ushort* __restrict__ wbf,
                         const float* __restrict__ bias,
                         float* __restrict__ out) {
    // xs tile: [t][ck] bf16, XOR-swizzled cols: col' = col ^ ((t&15)<<3). 24 KB.
    __shared__ ushort xs[TT][CK];

    const int tid  = threadIdx.x;
    const int lane = tid & 63;
    const int wv   = tid >> 6;          // wave 0..3 -> o-rows [wv*32, wv*32+32)
    const int bid  = blockIdx.x;
    // XCD-chunked swizzle over 2048 blocks: XCD k (= bid%8) owns lb in
    // [k*256,(k+1)*256) = b in {2k,2k+1}, all 128 t-tiles. Bijective.
    const int lb   = (bid & 7) * 256 + (bid >> 3);
    const int b    = lb >> 7;
    const int t0   = (lb & 127) * TT;

    // ---- build xs tile: unit = (t, c-group of 8). 512 units / 256 threads. ----
    for (int it = 0; it < 2; ++it) {
        const int u  = tid + it * 256;
        const int t  = u & (TT - 1);
        const int cg = u >> 5;                 // 0..15
        const int gt = t0 + t;

        float g0[3], g1[3];
        int   U[3];
#pragma unroll
        for (int k = 0; k < 3; ++k) {
            float ofv = 0.f, mv = 0.f;
            if (gt < LOUT) {
                ofv = offs[((size_t)b * LOUT + gt) * 3 + k];
                mv  = mask[((size_t)b * 3 + k) * LOUT + gt];
            }
            const float gtf = (float)gt;
            float T = (gtf + (float)k) + ofv;          // exact ref op order
            T = fminf(fmaxf(T, gtf), gtf + 2.0f);      // clamp to receptive field
            int Ui = (int)floorf(T);
            if (Ui > LL - 2) Ui = LL - 2;
            const float Uf = (float)Ui;
            g0[k] = fmaxf(0.f, 1.f - fabsf(Uf - T)) * mv;
            g1[k] = fmaxf(0.f, 1.f - fabsf(Uf + 1.f - T)) * mv;
            U[k] = Ui;
        }

        ushort vals[24];
#pragma unroll
        for (int ci = 0; ci < 8; ++ci) {
            const float* xr = x + ((size_t)b * CI + cg * 8 + ci) * LL;
#pragma unroll
            for (int k = 0; k < 3; ++k) {
                const float x0 = xr[U[k]];
                const float x1 = xr[U[k] + 1];         // U <= LL-2 -> in bounds
                vals[ci * 3 + k] = f2bf(g0[k] * x0 + g1[k] * x1);
            }
        }
        uint dw[12];
#pragma unroll
        for (int j = 0; j < 12; ++j)
            dw[j] = (uint)vals[2 * j] | ((uint)vals[2 * j + 1] << 16);
        const int swz = (t & 15) << 3;
#pragma unroll
        for (int j = 0; j < 3; ++j) {
            const int col = (cg * 24 + j * 8) ^ swz;   // 8-aligned, bijective
            uint4 q; q.x = dw[4*j]; q.y = dw[4*j+1]; q.z = dw[4*j+2]; q.w = dw[4*j+3];
            *(uint4*)(&xs[t][col]) = q;
        }
    }
    __syncthreads();

    // ---- GEMM: 12 k-steps of 32; wave owns 32 o-rows x 32 t ----
    floatx4 zero4 = {0.f, 0.f, 0.f, 0.f};
    floatx4 acc[2][2];
#pragma unroll
    for (int mf = 0; mf < 2; ++mf)
#pragma unroll
        for (int nf = 0; nf < 2; ++nf) acc[mf][nf] = zero4;

    const int arow = wv * 32 + (lane & 15);    // A row = lane&15
    const int ack  = (lane >> 4) * 8;          // A k  = (lane>>4)*8 + j
    const int bswz = (lane & 15) << 3;

#pragma unroll 2
    for (int ks = 0; ks < 12; ++ks) {
        short8 afr[2];
#pragma unroll
        for (int mf = 0; mf < 2; ++mf)
            afr[mf] = *(const short8*)(wbf + (size_t)(arow + mf * 16) * CK + ks * 32 + ack);
        short8 bfr[2];
#pragma unroll
        for (int nf = 0; nf < 2; ++nf) {
            const int tb  = nf * 16 + (lane & 15);     // B col = lane&15
            const int col = (ks * 32 + (lane >> 4) * 8) ^ bswz;
            bfr[nf] = *(const short8*)(&xs[tb][col]);
        }
#pragma unroll
        for (int mf = 0; mf < 2; ++mf)
#pragma unroll
            for (int nf = 0; nf < 2; ++nf)
                acc[mf][nf] = __builtin_amdgcn_mfma_f32_16x16x32_bf16(
                    afr[mf], bfr[nf], acc[mf][nf], 0, 0, 0);
    }

    // ---- epilogue: direct stores. D: col(t)=lane&15, row(o)=(lane>>4)*4+r.
    // R7 measured this clean (WRITE 32.9 MB = 1.02x out). ----
#pragma unroll
    for (int mf = 0; mf < 2; ++mf) {
#pragma unroll
        for (int r = 0; r < 4; ++r) {
            const int o  = wv * 32 + mf * 16 + (lane >> 4) * 4 + r;
            const float bv = bias[o];
            float* orow = out + ((size_t)b * CO + o) * LOUT;
#pragma unroll
            for (int nf = 0; nf < 2; ++nf) {
                const int gt = t0 + nf * 16 + (lane & 15);
                if (gt < LOUT) orow[gt] = acc[mf][nf][r] + bv;
            }
        }
    }
}

extern "C" void kernel_launch(void* const* d_in, const int* in_sizes, int n_in,
                              void* d_out, int out_size, void* d_ws, size_t ws_size,
                              hipStream_t stream) {
    const float* x    = (const float*)d_in[0];
    const float* offs = (const float*)d_in[1];
    const float* mask = (const float*)d_in[2];
    const float* w    = (const float*)d_in[3];
    const float* bias = (const float*)d_in[4];
    float* out = (float*)d_out;
    ushort* wbf = (ushort*)d_ws;             // 98.3 KB of scratch

    wcvt_kernel<<<dim3(CO * CI * 3 / (256 * 8)), dim3(256), 0, stream>>>(w, wbf);
    dim3 grid(BB * NTILE);   // 2048 blocks
    dim3 block(256);
    dconv1d_mfma_kernel<<<grid, block, 0, stream>>>(x, offs, mask, wbf, bias, out);
}

// Round 9
// 48.891 us; speedup vs baseline: 1.2517x; 1.0342x over previous
//
#include <hip/hip_runtime.h>

// Deformable Conv1d, two-stage MFMA formulation.
//   GEMM1 (per k): xs_k[c][t] = sum_tau x[c][t0+tau] * S_k[tau][t],
//     S_k[t+d][t] = coef[k][d][t]  (4-banded sampling matrix in LDS, bf16)
//     A = x direct from global (tau contiguous -> NO gathers, no transpose)
//   GEMM2: out[o][t] = sum_{ck'} w[o][ck'] * xs[ck'][t],  ck' = k*128+c
// R9: replaces the gather/interp instruction storm (~400 VMEM + 800 VALU per
//     block, the common structure of R2-R8's latency wall) with MFMA.
#define BB 16
#define CI 128
#define CO 128
#define LL 4096
#define LOUT 4094
#define CK 384            // GEMM2 K = 3*128
#define TT 32             // t-tile per block
#define NTILE 128
#define STS 72            // S_k row stride (ushort): 144B rows, 16B-aligned
#define XSS 408           // xs row stride (ushort): 816B rows, 16B-aligned

typedef short short8 __attribute__((ext_vector_type(8)));
typedef float floatx4 __attribute__((ext_vector_type(4)));

__device__ __forceinline__ ushort f2bf(float f) {   // RNE f32 -> bf16
    union { float f; uint u; } v; v.f = f;
    uint r = v.u + 0x7FFFu + ((v.u >> 16) & 1u);
    return (ushort)(r >> 16);
}
__device__ __forceinline__ uint pk(ushort a, ushort b) {
    return (uint)a | ((uint)b << 16);
}

// ---- w[o][c][k] f32 -> wbf2[o][k*128+c] bf16 (16384 threads) ----
__global__ __launch_bounds__(256)
void wcvt2_kernel(const float* __restrict__ w, ushort* __restrict__ wbf2) {
    const int i = blockIdx.x * 256 + threadIdx.x;   // o*128 + c
    const int o = i >> 7, c = i & 127;
    const float w0 = w[i * 3 + 0], w1 = w[i * 3 + 1], w2 = w[i * 3 + 2];
    wbf2[o * CK +       c] = f2bf(w0);
    wbf2[o * CK + 128 + c] = f2bf(w1);
    wbf2[o * CK + 256 + c] = f2bf(w2);
}

__global__ __launch_bounds__(256, 4)
void dconv1d_mfma2_kernel(const float* __restrict__ x,
                          const float* __restrict__ offs,
                          const float* __restrict__ mask,
                          const ushort* __restrict__ wbf2,
                          const float* __restrict__ bias,
                          float* __restrict__ out) {
    __shared__ ushort St[3][TT][STS];   // 13.8 KB sampling matrices (zero-filled)
    __shared__ ushort xs[TT][XSS];      // 26.1 KB xs tile [t][k*128+c]

    const int tid  = threadIdx.x;
    const int lane = tid & 63;
    const int wv   = tid >> 6;
    const int bid  = blockIdx.x;
    // XCD-chunked swizzle: XCD (bid&7) owns lb in [k*256,(k+1)*256) -> 2 b's.
    const int lb   = (bid & 7) * 256 + (bid >> 3);
    const int b    = lb >> 7;
    const int t0   = (lb & 127) * TT;

    // ---- phase 0: zero St ----
    uint* stz = (uint*)&St[0][0][0];
#pragma unroll
    for (int i = 0; i < 14; ++i) {
        const int j = tid + i * 256;
        if (j < 3 * TT * STS / 2) stz[j] = 0;
    }

    // ---- A-frags for GEMM1 (shared across k): x[c-row][t0 + tau], bf16.
    // A[row=c][kdim=tau]: lane row = lane&15, tau chunk = (lane>>4)*8. ----
    short8 axf[2][2];    // [mf][ks1]
    {
        const int arow = wv * 32 + (lane & 15);
#pragma unroll
        for (int mf = 0; mf < 2; ++mf)
#pragma unroll
            for (int ks1 = 0; ks1 < 2; ++ks1) {
                int tb = t0 + ks1 * 32 + ((lane >> 4) << 3);
                if (tb > LL - 8) tb = LL - 8;   // clamp; affected lanes hit zero St
                const float* p = x + ((size_t)b * CI + arow + mf * 16) * LL + tb;
                floatx4 v0 = *(const floatx4*)(p);
                floatx4 v1 = *(const floatx4*)(p + 4);
                union { uint u[4]; short8 s; } r;
                r.u[0] = pk(f2bf(v0[0]), f2bf(v0[1]));
                r.u[1] = pk(f2bf(v0[2]), f2bf(v0[3]));
                r.u[2] = pk(f2bf(v1[0]), f2bf(v1[1]));
                r.u[3] = pk(f2bf(v1[2]), f2bf(v1[3]));
                axf[mf][ks1] = r.s;
            }
    }
    __syncthreads();   // St zeroed

    // ---- phase 1: coef -> St band (96 units; exact reference fp32 op order) ----
    if (tid < 3 * TT) {
        const int t  = tid & (TT - 1);
        const int k  = tid >> 5;               // 0..2
        const int gt = t0 + t;
        if (gt < LOUT) {
            const float ofv = offs[((size_t)b * LOUT + gt) * 3 + k];
            const float mv  = mask[((size_t)b * 3 + k) * LOUT + gt];
            const float gtf = (float)gt;
            float T = (gtf + (float)k) + ofv;          // t0s + dil_pos + offsets
            T = fminf(fmaxf(T, gtf), gtf + 2.0f);      // clamp to receptive field
            int U = (int)floorf(T);
            if (U > LL - 2) U = LL - 2;                // clip(., 0, l-2)
            const float Uf = (float)U;
            const float G0 = fmaxf(0.f, 1.f - fabsf(Uf - T)) * mv;
            const float G1 = fmaxf(0.f, 1.f - fabsf(Uf + 1.f - T)) * mv;
            const int d0 = U - gt;                     // 0..2
            const float c0 = (d0 == 0) ? G0 : 0.f;
            const float c1 = (d0 == 0) ? G1 : ((d0 == 1) ? G0 : 0.f);
            const float c2 = (d0 == 1) ? G1 : ((d0 == 2) ? G0 : 0.f);
            const float c3 = (d0 == 2) ? G1 : 0.f;
            St[k][t][t + 0] = f2bf(c0);
            St[k][t][t + 1] = f2bf(c1);
            St[k][t][t + 2] = f2bf(c2);
            St[k][t][t + 3] = f2bf(c3);
        }
    }
    __syncthreads();   // St ready

    // ---- GEMM1 (per k): D[c][t], M=128c (4 waves x mf2), N=32t (nf2), K=64tau ----
#pragma unroll
    for (int k = 0; k < 3; ++k) {
        short8 bf1[2][2];   // [nf][ks1]
#pragma unroll
        for (int nf = 0; nf < 2; ++nf)
#pragma unroll
            for (int ks1 = 0; ks1 < 2; ++ks1)
                bf1[nf][ks1] = *(const short8*)
                    (&St[k][nf * 16 + (lane & 15)][ks1 * 32 + ((lane >> 4) << 3)]);
        floatx4 a1[2][2];
#pragma unroll
        for (int mf = 0; mf < 2; ++mf)
#pragma unroll
            for (int nf = 0; nf < 2; ++nf) {
                floatx4 z = {0.f, 0.f, 0.f, 0.f};
                a1[mf][nf] = z;
            }
#pragma unroll
        for (int ks1 = 0; ks1 < 2; ++ks1)
#pragma unroll
            for (int mf = 0; mf < 2; ++mf)
#pragma unroll
                for (int nf = 0; nf < 2; ++nf)
                    a1[mf][nf] = __builtin_amdgcn_mfma_f32_16x16x32_bf16(
                        axf[mf][ks1], bf1[nf][ks1], a1[mf][nf], 0, 0, 0);
        // D: col(t)=lane&15, row(c)=(lane>>4)*4+r. Write 4 consecutive c -> b64.
#pragma unroll
        for (int mf = 0; mf < 2; ++mf)
#pragma unroll
            for (int nf = 0; nf < 2; ++nf) {
                const int tcol = nf * 16 + (lane & 15);
                const int cb   = wv * 32 + mf * 16 + ((lane >> 4) << 2);
                uint2 q;
                q.x = pk(f2bf(a1[mf][nf][0]), f2bf(a1[mf][nf][1]));
                q.y = pk(f2bf(a1[mf][nf][2]), f2bf(a1[mf][nf][3]));
                *(uint2*)(&xs[tcol][k * 128 + cb]) = q;
            }
    }
    __syncthreads();   // xs ready

    // ---- GEMM2: out[o][t] = sum_ck' wbf2[o][ck'] xs[ck'][t], 12 k-steps ----
    floatx4 acc[2][2];
#pragma unroll
    for (int mf = 0; mf < 2; ++mf)
#pragma unroll
        for (int nf = 0; nf < 2; ++nf) {
            floatx4 z = {0.f, 0.f, 0.f, 0.f};
            acc[mf][nf] = z;
        }
    const int arow = wv * 32 + (lane & 15);
    const int ack  = (lane >> 4) << 3;
#pragma unroll 4
    for (int ks = 0; ks < 12; ++ks) {
        short8 afr[2];
#pragma unroll
        for (int mf = 0; mf < 2; ++mf)
            afr[mf] = *(const short8*)(wbf2 + (size_t)(arow + mf * 16) * CK + ks * 32 + ack);
        short8 bfr[2];
#pragma unroll
        for (int nf = 0; nf < 2; ++nf)
            bfr[nf] = *(const short8*)(&xs[nf * 16 + (lane & 15)][ks * 32 + ack]);
#pragma unroll
        for (int mf = 0; mf < 2; ++mf)
#pragma unroll
            for (int nf = 0; nf < 2; ++nf)
                acc[mf][nf] = __builtin_amdgcn_mfma_f32_16x16x32_bf16(
                    afr[mf], bfr[nf], acc[mf][nf], 0, 0, 0);
    }

    // ---- epilogue: direct stores (R7/R8 measured clean: WRITE ~1.02x out) ----
#pragma unroll
    for (int mf = 0; mf < 2; ++mf) {
#pragma unroll
        for (int r = 0; r < 4; ++r) {
            const int o  = wv * 32 + mf * 16 + ((lane >> 4) << 2) + r;
            const float bv = bias[o];
            float* orow = out + ((size_t)b * CO + o) * LOUT;
#pragma unroll
            for (int nf = 0; nf < 2; ++nf) {
                const int gt = t0 + nf * 16 + (lane & 15);
                if (gt < LOUT) orow[gt] = acc[mf][nf][r] + bv;
            }
        }
    }
}

extern "C" void kernel_launch(void* const* d_in, const int* in_sizes, int n_in,
                              void* d_out, int out_size, void* d_ws, size_t ws_size,
                              hipStream_t stream) {
    const float* x    = (const float*)d_in[0];
    const float* offs = (const float*)d_in[1];
    const float* mask = (const float*)d_in[2];
    const float* w    = (const float*)d_in[3];
    const float* bias = (const float*)d_in[4];
    float* out = (float*)d_out;
    ushort* wbf2 = (ushort*)d_ws;            // 98.3 KB

    wcvt2_kernel<<<dim3(CO * CI / 256), dim3(256), 0, stream>>>(w, wbf2);
    dconv1d_mfma2_kernel<<<dim3(BB * NTILE), dim3(256), 0, stream>>>(
        x, offs, mask, wbf2, bias, out);
}

// Round 10
// 46.027 us; speedup vs baseline: 1.3296x; 1.0622x over previous
//
#include <hip/hip_runtime.h>

// Deformable Conv1d, two-stage MFMA formulation + 2-tile software pipeline.
//   GEMM1 (per k): xs_k[c][t] = sum_tau x[c][t0+tau] * S_k[tau][t]  (banded S in LDS)
//   GEMM2:         out[o][t]  = sum_{ck'} w[o][ck'] * xs[ck'][t],  ck' = k*128+c
// R10: Little's-law fix — per-CU queue depth was ~2 lines (serial chains).
//   1024 blocks x 2 tiles: ALL global reads (3 x-chunks + both tiles' offs/mask)
//   issued back-to-back in the prologue; tile1 latency hides under tile0 compute.
//   St zeroed once (band positions tile-invariant, values overwritten).
#define BB 16
#define CI 128
#define CO 128
#define LL 4096
#define LOUT 4094
#define CK 384            // GEMM2 K = 3*128
#define TT 32             // t per tile
#define NT 2              // tiles per block
#define CHUNK 64          // NT*TT, t per block
#define STS 72            // S_k row stride (ushort)
#define XSS 408           // xs row stride (ushort)

typedef short short8 __attribute__((ext_vector_type(8)));
typedef float floatx4 __attribute__((ext_vector_type(4)));

__device__ __forceinline__ ushort f2bf(float f) {   // RNE f32 -> bf16
    union { float f; uint u; } v; v.f = f;
    uint r = v.u + 0x7FFFu + ((v.u >> 16) & 1u);
    return (ushort)(r >> 16);
}
__device__ __forceinline__ uint pk(ushort a, ushort b) {
    return (uint)a | ((uint)b << 16);
}
__device__ __forceinline__ short8 cvt8(floatx4 v0, floatx4 v1) {
    union { uint u[4]; short8 s; } r;
    r.u[0] = pk(f2bf(v0[0]), f2bf(v0[1]));
    r.u[1] = pk(f2bf(v0[2]), f2bf(v0[3]));
    r.u[2] = pk(f2bf(v1[0]), f2bf(v1[1]));
    r.u[3] = pk(f2bf(v1[2]), f2bf(v1[3]));
    return r.s;
}

// ---- w[o][c][k] f32 -> wbf2[o][k*128+c] bf16 ----
__global__ __launch_bounds__(256)
void wcvt2_kernel(const float* __restrict__ w, ushort* __restrict__ wbf2) {
    const int i = blockIdx.x * 256 + threadIdx.x;   // o*128 + c
    const int o = i >> 7, c = i & 127;
    const float w0 = w[i * 3 + 0], w1 = w[i * 3 + 1], w2 = w[i * 3 + 2];
    wbf2[o * CK +       c] = f2bf(w0);
    wbf2[o * CK + 128 + c] = f2bf(w1);
    wbf2[o * CK + 256 + c] = f2bf(w2);
}

__global__ __launch_bounds__(256, 4)
void dconv1d_pipe_kernel(const float* __restrict__ x,
                         const float* __restrict__ offs,
                         const float* __restrict__ mask,
                         const ushort* __restrict__ wbf2,
                         const float* __restrict__ bias,
                         float* __restrict__ out) {
    __shared__ ushort St[3][TT][STS];   // 13.5 KB sampling matrices
    __shared__ ushort xs[TT][XSS];      // 25.5 KB xs tile [t][k*128+c]

    const int tid  = threadIdx.x;
    const int lane = tid & 63;
    const int wv   = tid >> 6;
    const int bid  = blockIdx.x;
    // XCD-chunked swizzle over 1024: XCD (bid&7) owns lb [k*128,(k+1)*128) -> 2 b's.
    const int lb   = (bid & 7) * 128 + (bid >> 3);
    const int b    = lb >> 6;
    const int t0b  = (lb & 63) * CHUNK;

    const int arow  = wv * 32 + (lane & 15);    // A row (c), GEMM1
    const int acol8 = (lane >> 4) << 3;         // k-dim subchunk

    // ---- prologue: issue ALL global reads back-to-back (deep MLP) ----
    floatx4 xv[3][2][2];   // [chunk][mf][pair], raw f32; static idx (unrolled)
#pragma unroll
    for (int ch = 0; ch < 3; ++ch)
#pragma unroll
        for (int mf = 0; mf < 2; ++mf) {
            int tb = t0b + ch * 32 + acol8;
            if (tb > LL - 8) tb = LL - 8;       // clamped lanes hit zero S entries
            const float* p = x + ((size_t)b * CI + arow + mf * 16) * LL + tb;
            xv[ch][mf][0] = *(const floatx4*)(p);
            xv[ch][mf][1] = *(const floatx4*)(p + 4);
        }
    const int ct  = tid & 31;                   // coef unit t (tid<96)
    const int ck_ = (tid >> 5) < 3 ? (tid >> 5) : 0;
    float ofv[NT], mv[NT];
#pragma unroll
    for (int i = 0; i < NT; ++i) {
        ofv[i] = 0.f; mv[i] = 0.f;
        const int gt = t0b + i * TT + ct;
        if (tid < 96 && gt < LOUT) {
            ofv[i] = offs[((size_t)b * LOUT + gt) * 3 + ck_];
            mv[i]  = mask[((size_t)b * 3 + ck_) * LOUT + gt];
        }
    }

    // ---- zero St once (band positions identical both tiles) ----
    uint* stz = (uint*)&St[0][0][0];
    for (int i2 = tid; i2 < 3 * TT * STS / 2; i2 += 256) stz[i2] = 0;

    // current A-frags (chunks 0,1); chunk 2 stays raw until tile1
    short8 axf[2][2];
#pragma unroll
    for (int mf = 0; mf < 2; ++mf) {
        axf[mf][0] = cvt8(xv[0][mf][0], xv[0][mf][1]);
        axf[mf][1] = cvt8(xv[1][mf][0], xv[1][mf][1]);
    }
    __syncthreads();   // St zero visible before band writes

#pragma unroll
    for (int it = 0; it < NT; ++it) {
        const int t0 = t0b + it * TT;

        // ---- coef -> St band (96 units; exact reference fp32 op order) ----
        if (tid < 96) {
            const int gt = t0 + ct;
            float c0 = 0.f, c1 = 0.f, c2 = 0.f, c3 = 0.f;
            if (gt < LOUT) {
                const float gtf = (float)gt;
                float T = (gtf + (float)ck_) + ofv[it];
                T = fminf(fmaxf(T, gtf), gtf + 2.0f);
                int U = (int)floorf(T);
                if (U > LL - 2) U = LL - 2;
                const float Uf = (float)U;
                const float G0 = fmaxf(0.f, 1.f - fabsf(Uf - T)) * mv[it];
                const float G1 = fmaxf(0.f, 1.f - fabsf(Uf + 1.f - T)) * mv[it];
                const int d0 = U - gt;
                c0 = (d0 == 0) ? G0 : 0.f;
                c1 = (d0 == 0) ? G1 : ((d0 == 1) ? G0 : 0.f);
                c2 = (d0 == 1) ? G1 : ((d0 == 2) ? G0 : 0.f);
                c3 = (d0 == 2) ? G1 : 0.f;
            }
            St[ck_][ct][ct + 0] = f2bf(c0);     // unconditional: overwrites old tile
            St[ck_][ct][ct + 1] = f2bf(c1);
            St[ck_][ct][ct + 2] = f2bf(c2);
            St[ck_][ct][ct + 3] = f2bf(c3);
        }
        __syncthreads();   // St ready; also fences tile(it-1) GEMM2 xs-reads

        // ---- GEMM1 (per k): D[c][t] = x-window . S_k, K=64 ----
#pragma unroll
        for (int k = 0; k < 3; ++k) {
            short8 bf1[2][2];
#pragma unroll
            for (int nf = 0; nf < 2; ++nf)
#pragma unroll
                for (int ks1 = 0; ks1 < 2; ++ks1)
                    bf1[nf][ks1] = *(const short8*)
                        (&St[k][nf * 16 + (lane & 15)][ks1 * 32 + acol8]);
            floatx4 a1[2][2];
#pragma unroll
            for (int mf = 0; mf < 2; ++mf)
#pragma unroll
                for (int nf = 0; nf < 2; ++nf) {
                    floatx4 z = {0.f, 0.f, 0.f, 0.f};
                    a1[mf][nf] = z;
                }
#pragma unroll
            for (int ks1 = 0; ks1 < 2; ++ks1)
#pragma unroll
                for (int mf = 0; mf < 2; ++mf)
#pragma unroll
                    for (int nf = 0; nf < 2; ++nf)
                        a1[mf][nf] = __builtin_amdgcn_mfma_f32_16x16x32_bf16(
                            axf[mf][ks1], bf1[nf][ks1], a1[mf][nf], 0, 0, 0);
            // D: col(t)=lane&15, row(c)=(lane>>4)*4+r -> xs[t][k*128+c], b64
#pragma unroll
            for (int mf = 0; mf < 2; ++mf)
#pragma unroll
                for (int nf = 0; nf < 2; ++nf) {
                    const int tcol = nf * 16 + (lane & 15);
                    const int cb   = wv * 32 + mf * 16 + ((lane >> 4) << 2);
                    uint2 q;
                    q.x = pk(f2bf(a1[mf][nf][0]), f2bf(a1[mf][nf][1]));
                    q.y = pk(f2bf(a1[mf][nf][2]), f2bf(a1[mf][nf][3]));
                    *(uint2*)(&xs[tcol][k * 128 + cb]) = q;
                }
        }
        __syncthreads();   // xs ready

        // ---- GEMM2: out[o][t], 12 k-steps of 32 ----
        floatx4 acc[2][2];
#pragma unroll
        for (int mf = 0; mf < 2; ++mf)
#pragma unroll
            for (int nf = 0; nf < 2; ++nf) {
                floatx4 z = {0.f, 0.f, 0.f, 0.f};
                acc[mf][nf] = z;
            }
#pragma unroll 4
        for (int ks = 0; ks < 12; ++ks) {
            short8 afr[2];
#pragma unroll
            for (int mf = 0; mf < 2; ++mf)
                afr[mf] = *(const short8*)(wbf2 + (size_t)(arow + mf * 16) * CK + ks * 32 + acol8);
            short8 bfr[2];
#pragma unroll
            for (int nf = 0; nf < 2; ++nf)
                bfr[nf] = *(const short8*)(&xs[nf * 16 + (lane & 15)][ks * 32 + acol8]);
#pragma unroll
            for (int mf = 0; mf < 2; ++mf)
#pragma unroll
                for (int nf = 0; nf < 2; ++nf)
                    acc[mf][nf] = __builtin_amdgcn_mfma_f32_16x16x32_bf16(
                        afr[mf], bfr[nf], acc[mf][nf], 0, 0, 0);
        }

        // ---- epilogue: direct stores (measured clean, WRITE ~1.02x out) ----
#pragma unroll
        for (int mf = 0; mf < 2; ++mf)
#pragma unroll
            for (int r = 0; r < 4; ++r) {
                const int o  = wv * 32 + mf * 16 + ((lane >> 4) << 2) + r;
                const float bv = bias[o];
                float* orow = out + ((size_t)b * CO + o) * LOUT;
#pragma unroll
                for (int nf = 0; nf < 2; ++nf) {
                    const int gt = t0 + nf * 16 + (lane & 15);
                    if (gt < LOUT) orow[gt] = acc[mf][nf][r] + bv;
                }
            }

        // ---- rotate A-frags: tile1 window = chunks 1,2 ----
        if (it + 1 < NT) {
#pragma unroll
            for (int mf = 0; mf < 2; ++mf) {
                axf[mf][0] = axf[mf][1];
                axf[mf][1] = cvt8(xv[2][mf][0], xv[2][mf][1]);
            }
        }
    }
}

extern "C" void kernel_launch(void* const* d_in, const int* in_sizes, int n_in,
                              void* d_out, int out_size, void* d_ws, size_t ws_size,
                              hipStream_t stream) {
    const float* x    = (const float*)d_in[0];
    const float* offs = (const float*)d_in[1];
    const float* mask = (const float*)d_in[2];
    const float* w    = (const float*)d_in[3];
    const float* bias = (const float*)d_in[4];
    float* out = (float*)d_out;
    ushort* wbf2 = (ushort*)d_ws;            // 98.3 KB

    wcvt2_kernel<<<dim3(CO * CI / 256), dim3(256), 0, stream>>>(w, wbf2);
    dconv1d_pipe_kernel<<<dim3(1024), dim3(256), 0, stream>>>(
        x, offs, mask, wbf2, bias, out);
}

// Round 11
// 33.985 us; speedup vs baseline: 1.8007x; 1.3543x over previous
//
#include <hip/hip_runtime.h>

// Deformable Conv1d, two-stage MFMA + persistent 4-tile pipeline.
//   GEMM1 (per k): xs_k[c][t] = sum_tau x[c][t0+tau] * S_k[tau][t]  (banded S in LDS)
//   GEMM2:         out[o][t]  = sum_{ck'} w[o][ck'] * xs[ck'][t],  ck' = k*128+c
// R11: 512-thread blocks (8 waves, wave owns 16 rows), 4 tiles/block, 512 blocks
//   = 2/CU in one round. wbf2 A-frags hoisted to regs ONCE (48 VGPR, static idx)
//   -> GEMM2 inner loop has ZERO global loads. Next tile's x/offs/mask issued a
//   full tile early (T14). Attacks the measured stall-dominance (R5-R10: all
//   pipes <13%, ~1.9 KB/CU memory in flight).
#define BB 16
#define CI 128
#define CO 128
#define LL 4096
#define LOUT 4094
#define CK 384            // GEMM2 K = 3*128
#define TT 32             // t per tile
#define NTPB 4            // tiles per block
#define STS 72            // S_k row stride (ushort)
#define XSS 408           // xs row stride (ushort)

typedef short short8 __attribute__((ext_vector_type(8)));
typedef float floatx4 __attribute__((ext_vector_type(4)));

__device__ __forceinline__ ushort f2bf(float f) {   // RNE f32 -> bf16
    union { float f; uint u; } v; v.f = f;
    uint r = v.u + 0x7FFFu + ((v.u >> 16) & 1u);
    return (ushort)(r >> 16);
}
__device__ __forceinline__ uint pk(ushort a, ushort b) {
    return (uint)a | ((uint)b << 16);
}
__device__ __forceinline__ short8 cvt8(floatx4 v0, floatx4 v1) {
    union { uint u[4]; short8 s; } r;
    r.u[0] = pk(f2bf(v0[0]), f2bf(v0[1]));
    r.u[1] = pk(f2bf(v0[2]), f2bf(v0[3]));
    r.u[2] = pk(f2bf(v1[0]), f2bf(v1[1]));
    r.u[3] = pk(f2bf(v1[2]), f2bf(v1[3]));
    return r.s;
}

// ---- w[o][c][k] f32 -> wbf2[o][k*128+c] bf16 ----
__global__ __launch_bounds__(256)
void wcvt2_kernel(const float* __restrict__ w, ushort* __restrict__ wbf2) {
    const int i = blockIdx.x * 256 + threadIdx.x;   // o*128 + c
    const int o = i >> 7, c = i & 127;
    const float w0 = w[i * 3 + 0], w1 = w[i * 3 + 1], w2 = w[i * 3 + 2];
    wbf2[o * CK +       c] = f2bf(w0);
    wbf2[o * CK + 128 + c] = f2bf(w1);
    wbf2[o * CK + 256 + c] = f2bf(w2);
}

__global__ __launch_bounds__(512, 4)
void dconv1d_pers_kernel(const float* __restrict__ x,
                         const float* __restrict__ offs,
                         const float* __restrict__ mask,
                         const ushort* __restrict__ wbf2,
                         const float* __restrict__ bias,
                         float* __restrict__ out) {
    __shared__ ushort St[3][TT][STS];   // 13.5 KB sampling matrices
    __shared__ ushort xs[TT][XSS];      // 25.5 KB xs tile [t][k*128+c]

    const int tid  = threadIdx.x;
    const int lane = tid & 63;
    const int wv   = tid >> 6;          // 0..7; wave owns rows wv*16..wv*16+15
    const int bid  = blockIdx.x;
    // XCD-chunked swizzle over 512: XCD (bid&7) owns lb [k*64,(k+1)*64) -> 2 b's.
    const int lb   = (bid & 7) * 64 + (bid >> 3);
    const int b    = lb >> 5;
    const int t0b  = (lb & 31) * (TT * NTPB);   // 128-t stripe

    const int row16 = wv * 16 + (lane & 15);    // o (GEMM2 A) and c (GEMM1 A)
    const int acol8 = (lane >> 4) << 3;         // k-dim subchunk

    // ---- prologue: issue ALL reusable/tile0+1 loads back-to-back ----
    short8 afr[12];                             // persistent A (GEMM2), 48 VGPR
#pragma unroll
    for (int ks = 0; ks < 12; ++ks)
        afr[ks] = *(const short8*)(wbf2 + (size_t)row16 * CK + ks * 32 + acol8);

    const float* xrow = x + ((size_t)b * CI + row16) * LL;
    floatx4 c0a, c0b, c1a, c1b, xn0, xn1;
    {
        const int tb0 = t0b + acol8;            // chunks 0,1 never OOB
        const int tb1 = t0b + 32 + acol8;
        int tb2 = t0b + 64 + acol8; if (tb2 > LL - 8) tb2 = LL - 8;
        c0a = *(const floatx4*)(xrow + tb0); c0b = *(const floatx4*)(xrow + tb0 + 4);
        c1a = *(const floatx4*)(xrow + tb1); c1b = *(const floatx4*)(xrow + tb1 + 4);
        xn0 = *(const floatx4*)(xrow + tb2); xn1 = *(const floatx4*)(xrow + tb2 + 4);
    }

    const int ct  = tid & 31;                   // coef unit t (tid<96)
    const int ck_ = (tid >> 5) < 3 ? (tid >> 5) : 0;
    float ofc = 0.f, mvc = 0.f, ofn = 0.f, mvn = 0.f;
    if (tid < 96) {
        const int g0 = t0b + ct;                // tile0: always < LOUT
        ofc = offs[((size_t)b * LOUT + g0) * 3 + ck_];
        mvc = mask[((size_t)b * 3 + ck_) * LOUT + g0];
        const int g1 = t0b + TT + ct;
        if (g1 < LOUT) {
            ofn = offs[((size_t)b * LOUT + g1) * 3 + ck_];
            mvn = mask[((size_t)b * 3 + ck_) * LOUT + g1];
        }
    }

    float bv[4];                                // bias for wave's 16 o-rows
#pragma unroll
    for (int r = 0; r < 4; ++r)
        bv[r] = bias[wv * 16 + ((lane >> 4) << 2) + r];

    // ---- zero St once (band positions tile-invariant) ----
    {
        uint* stz = (uint*)&St[0][0][0];
        for (int i = tid; i < 3 * TT * STS / 2; i += 512) stz[i] = 0;
    }

    short8 axf0 = cvt8(c0a, c0b);               // current x window (2 chunks)
    short8 axf1 = cvt8(c1a, c1b);
    __syncthreads();                            // St zero visible

#pragma unroll 1
    for (int it = 0; it < NTPB; ++it) {
        const int t0 = t0b + it * TT;

        // ---- coef -> St band (96 units; exact reference fp32 op order) ----
        if (tid < 96) {
            const int gt = t0 + ct;
            float cc0 = 0.f, cc1 = 0.f, cc2 = 0.f, cc3 = 0.f;
            if (gt < LOUT) {
                const float gtf = (float)gt;
                float T = (gtf + (float)ck_) + ofc;
                T = fminf(fmaxf(T, gtf), gtf + 2.0f);
                int U = (int)floorf(T);
                if (U > LL - 2) U = LL - 2;
                const float Uf = (float)U;
                const float G0 = fmaxf(0.f, 1.f - fabsf(Uf - T)) * mvc;
                const float G1 = fmaxf(0.f, 1.f - fabsf(Uf + 1.f - T)) * mvc;
                const int d0 = U - gt;
                cc0 = (d0 == 0) ? G0 : 0.f;
                cc1 = (d0 == 0) ? G1 : ((d0 == 1) ? G0 : 0.f);
                cc2 = (d0 == 1) ? G1 : ((d0 == 2) ? G0 : 0.f);
                cc3 = (d0 == 2) ? G1 : 0.f;
            }
            St[ck_][ct][ct + 0] = f2bf(cc0);    // overwrites previous tile's band
            St[ck_][ct][ct + 1] = f2bf(cc1);
            St[ck_][ct][ct + 2] = f2bf(cc2);
            St[ck_][ct][ct + 3] = f2bf(cc3);
        }
        // rotate offs/mask; issue tile(it+2) loads (in flight across next tile)
        ofc = ofn; mvc = mvn;
        if (it + 2 < NTPB && tid < 96) {
            const int g = t0b + (it + 2) * TT + ct;
            ofn = 0.f; mvn = 0.f;
            if (g < LOUT) {
                ofn = offs[((size_t)b * LOUT + g) * 3 + ck_];
                mvn = mask[((size_t)b * 3 + ck_) * LOUT + g];
            }
        }
        __syncthreads();   // St ready; also fences tile(it-1)'s GEMM2 xs reads

        // ---- GEMM1 (per k): D[c][t] = x-window . S_k, K=64 ----
#pragma unroll
        for (int k = 0; k < 3; ++k) {
            floatx4 a1[2];
#pragma unroll
            for (int nf = 0; nf < 2; ++nf) {
                floatx4 z = {0.f, 0.f, 0.f, 0.f};
                a1[nf] = z;
            }
#pragma unroll
            for (int ks1 = 0; ks1 < 2; ++ks1) {
                const short8 a = ks1 ? axf1 : axf0;
                const short8 bfa = *(const short8*)
                    (&St[k][(lane & 15)][ks1 * 32 + acol8]);
                const short8 bfb = *(const short8*)
                    (&St[k][16 + (lane & 15)][ks1 * 32 + acol8]);
                a1[0] = __builtin_amdgcn_mfma_f32_16x16x32_bf16(a, bfa, a1[0], 0, 0, 0);
                a1[1] = __builtin_amdgcn_mfma_f32_16x16x32_bf16(a, bfb, a1[1], 0, 0, 0);
            }
            // D: col(t)=lane&15, row(c)=(lane>>4)*4+r -> xs[t][k*128+c], b64
#pragma unroll
            for (int nf = 0; nf < 2; ++nf) {
                const int tcol = nf * 16 + (lane & 15);
                const int cb   = wv * 16 + ((lane >> 4) << 2);
                uint2 q;
                q.x = pk(f2bf(a1[nf][0]), f2bf(a1[nf][1]));
                q.y = pk(f2bf(a1[nf][2]), f2bf(a1[nf][3]));
                *(uint2*)(&xs[tcol][k * 128 + cb]) = q;
            }
        }
        __syncthreads();   // xs ready

        // ---- rotate x-window; issue chunk(it+3) load (hides under GEMM2) ----
        if (it + 1 < NTPB) {
            axf0 = axf1;
            axf1 = cvt8(xn0, xn1);              // chunk(it+2), arrived a tile ago
            if (it + 3 <= NTPB) {               // only chunks 3,4 ever needed
                int tb = t0b + (it + 3) * 32 + acol8;
                if (tb > LL - 8) tb = LL - 8;
                xn0 = *(const floatx4*)(xrow + tb);
                xn1 = *(const floatx4*)(xrow + tb + 4);
            }
        }

        // ---- GEMM2: out[o][t], 12 k-steps, A from regs, B from LDS ----
        floatx4 acc[2];
#pragma unroll
        for (int nf = 0; nf < 2; ++nf) {
            floatx4 z = {0.f, 0.f, 0.f, 0.f};
            acc[nf] = z;
        }
#pragma unroll
        for (int ks = 0; ks < 12; ++ks) {
            const short8 bf0 = *(const short8*)(&xs[(lane & 15)][ks * 32 + acol8]);
            const short8 bf1 = *(const short8*)(&xs[16 + (lane & 15)][ks * 32 + acol8]);
            acc[0] = __builtin_amdgcn_mfma_f32_16x16x32_bf16(afr[ks], bf0, acc[0], 0, 0, 0);
            acc[1] = __builtin_amdgcn_mfma_f32_16x16x32_bf16(afr[ks], bf1, acc[1], 0, 0, 0);
        }

        // ---- epilogue: direct stores (measured clean: WRITE ~1.02x out) ----
#pragma unroll
        for (int r = 0; r < 4; ++r) {
            const int o = wv * 16 + ((lane >> 4) << 2) + r;
            float* orow = out + ((size_t)b * CO + o) * LOUT;
#pragma unroll
            for (int nf = 0; nf < 2; ++nf) {
                const int gt = t0 + nf * 16 + (lane & 15);
                if (gt < LOUT) orow[gt] = acc[nf][r] + bv[r];
            }
        }
    }
}

extern "C" void kernel_launch(void* const* d_in, const int* in_sizes, int n_in,
                              void* d_out, int out_size, void* d_ws, size_t ws_size,
                              hipStream_t stream) {
    const float* x    = (const float*)d_in[0];
    const float* offs = (const float*)d_in[1];
    const float* mask = (const float*)d_in[2];
    const float* w    = (const float*)d_in[3];
    const float* bias = (const float*)d_in[4];
    float* out = (float*)d_out;
    ushort* wbf2 = (ushort*)d_ws;            // 98.3 KB

    wcvt2_kernel<<<dim3(CO * CI / 256), dim3(256), 0, stream>>>(w, wbf2);
    dconv1d_pers_kernel<<<dim3(512), dim3(512), 0, stream>>>(
        x, offs, mask, wbf2, bias, out);
}

// Round 12
// 33.954 us; speedup vs baseline: 1.8023x; 1.0009x over previous
//
#include <hip/hip_runtime.h>

// Deformable Conv1d, two-stage MFMA + persistent 4-tile pipeline.
//   GEMM1 (per k): xs_k[c][t] = sum_tau x[c][t0+tau] * S_k[tau][t]  (banded S in LDS)
//   GEMM2:         out[o][t]  = sum_{ck'} w[o][ck'] * xs[ck'][t],  ck' = k*128+c
// R12 = R11 + ONE change: all __syncthreads() -> {s_waitcnt lgkmcnt(0); s_barrier}.
//   __syncthreads emits s_waitcnt vmcnt(0) before s_barrier -> every barrier
//   drained ALL in-flight global prefetches (2 barriers/tile!) = the measured
//   stall-dominance of R5-R11 (all pipes <13%, ~600B/CU outstanding). Raw
//   barrier keeps prefetches in flight; LDS handoffs only need lgkmcnt(0);
//   compiler still emits counted vmcnt at each global-load consumption point.
#define BB 16
#define CI 128
#define CO 128
#define LL 4096
#define LOUT 4094
#define CK 384            // GEMM2 K = 3*128
#define TT 32             // t per tile
#define NTPB 4            // tiles per block
#define STS 72            // S_k row stride (ushort)
#define XSS 408           // xs row stride (ushort)

// LDS-visibility barrier WITHOUT vmcnt(0) drain (T3/T4: counted-vmcnt discipline)
#define LDS_BARRIER() do { \
    asm volatile("s_waitcnt lgkmcnt(0)" ::: "memory"); \
    __builtin_amdgcn_s_barrier(); \
} while (0)

typedef short short8 __attribute__((ext_vector_type(8)));
typedef float floatx4 __attribute__((ext_vector_type(4)));

__device__ __forceinline__ ushort f2bf(float f) {   // RNE f32 -> bf16
    union { float f; uint u; } v; v.f = f;
    uint r = v.u + 0x7FFFu + ((v.u >> 16) & 1u);
    return (ushort)(r >> 16);
}
__device__ __forceinline__ uint pk(ushort a, ushort b) {
    return (uint)a | ((uint)b << 16);
}
__device__ __forceinline__ short8 cvt8(floatx4 v0, floatx4 v1) {
    union { uint u[4]; short8 s; } r;
    r.u[0] = pk(f2bf(v0[0]), f2bf(v0[1]));
    r.u[1] = pk(f2bf(v0[2]), f2bf(v0[3]));
    r.u[2] = pk(f2bf(v1[0]), f2bf(v1[1]));
    r.u[3] = pk(f2bf(v1[2]), f2bf(v1[3]));
    return r.s;
}

// ---- w[o][c][k] f32 -> wbf2[o][k*128+c] bf16 ----
__global__ __launch_bounds__(256)
void wcvt2_kernel(const float* __restrict__ w, ushort* __restrict__ wbf2) {
    const int i = blockIdx.x * 256 + threadIdx.x;   // o*128 + c
    const int o = i >> 7, c = i & 127;
    const float w0 = w[i * 3 + 0], w1 = w[i * 3 + 1], w2 = w[i * 3 + 2];
    wbf2[o * CK +       c] = f2bf(w0);
    wbf2[o * CK + 128 + c] = f2bf(w1);
    wbf2[o * CK + 256 + c] = f2bf(w2);
}

__global__ __launch_bounds__(512, 4)
void dconv1d_pers_kernel(const float* __restrict__ x,
                         const float* __restrict__ offs,
                         const float* __restrict__ mask,
                         const ushort* __restrict__ wbf2,
                         const float* __restrict__ bias,
                         float* __restrict__ out) {
    __shared__ ushort St[3][TT][STS];   // 13.5 KB sampling matrices
    __shared__ ushort xs[TT][XSS];      // 25.5 KB xs tile [t][k*128+c]

    const int tid  = threadIdx.x;
    const int lane = tid & 63;
    const int wv   = tid >> 6;          // 0..7; wave owns rows wv*16..wv*16+15
    const int bid  = blockIdx.x;
    // XCD-chunked swizzle over 512: XCD (bid&7) owns lb [k*64,(k+1)*64) -> 2 b's.
    const int lb   = (bid & 7) * 64 + (bid >> 3);
    const int b    = lb >> 5;
    const int t0b  = (lb & 31) * (TT * NTPB);   // 128-t stripe

    const int row16 = wv * 16 + (lane & 15);    // o (GEMM2 A) and c (GEMM1 A)
    const int acol8 = (lane >> 4) << 3;         // k-dim subchunk

    // ---- prologue: issue ALL reusable/tile0+1 loads back-to-back ----
    short8 afr[12];                             // persistent A (GEMM2), 48 VGPR
#pragma unroll
    for (int ks = 0; ks < 12; ++ks)
        afr[ks] = *(const short8*)(wbf2 + (size_t)row16 * CK + ks * 32 + acol8);

    const float* xrow = x + ((size_t)b * CI + row16) * LL;
    floatx4 c0a, c0b, c1a, c1b, xn0, xn1;
    {
        const int tb0 = t0b + acol8;            // chunks 0,1 never OOB
        const int tb1 = t0b + 32 + acol8;
        int tb2 = t0b + 64 + acol8; if (tb2 > LL - 8) tb2 = LL - 8;
        c0a = *(const floatx4*)(xrow + tb0); c0b = *(const floatx4*)(xrow + tb0 + 4);
        c1a = *(const floatx4*)(xrow + tb1); c1b = *(const floatx4*)(xrow + tb1 + 4);
        xn0 = *(const floatx4*)(xrow + tb2); xn1 = *(const floatx4*)(xrow + tb2 + 4);
    }

    const int ct  = tid & 31;                   // coef unit t (tid<96)
    const int ck_ = (tid >> 5) < 3 ? (tid >> 5) : 0;
    float ofc = 0.f, mvc = 0.f, ofn = 0.f, mvn = 0.f;
    if (tid < 96) {
        const int g0 = t0b + ct;                // tile0: always < LOUT
        ofc = offs[((size_t)b * LOUT + g0) * 3 + ck_];
        mvc = mask[((size_t)b * 3 + ck_) * LOUT + g0];
        const int g1 = t0b + TT + ct;
        if (g1 < LOUT) {
            ofn = offs[((size_t)b * LOUT + g1) * 3 + ck_];
            mvn = mask[((size_t)b * 3 + ck_) * LOUT + g1];
        }
    }

    float bv[4];                                // bias for wave's 16 o-rows
#pragma unroll
    for (int r = 0; r < 4; ++r)
        bv[r] = bias[wv * 16 + ((lane >> 4) << 2) + r];

    // ---- zero St once (band positions tile-invariant) ----
    {
        uint* stz = (uint*)&St[0][0][0];
        for (int i = tid; i < 3 * TT * STS / 2; i += 512) stz[i] = 0;
    }

    short8 axf0 = cvt8(c0a, c0b);               // current x window (2 chunks)
    short8 axf1 = cvt8(c1a, c1b);
    LDS_BARRIER();                              // St zero visible

#pragma unroll 1
    for (int it = 0; it < NTPB; ++it) {
        const int t0 = t0b + it * TT;

        // ---- coef -> St band (96 units; exact reference fp32 op order) ----
        if (tid < 96) {
            const int gt = t0 + ct;
            float cc0 = 0.f, cc1 = 0.f, cc2 = 0.f, cc3 = 0.f;
            if (gt < LOUT) {
                const float gtf = (float)gt;
                float T = (gtf + (float)ck_) + ofc;
                T = fminf(fmaxf(T, gtf), gtf + 2.0f);
                int U = (int)floorf(T);
                if (U > LL - 2) U = LL - 2;
                const float Uf = (float)U;
                const float G0 = fmaxf(0.f, 1.f - fabsf(Uf - T)) * mvc;
                const float G1 = fmaxf(0.f, 1.f - fabsf(Uf + 1.f - T)) * mvc;
                const int d0 = U - gt;
                cc0 = (d0 == 0) ? G0 : 0.f;
                cc1 = (d0 == 0) ? G1 : ((d0 == 1) ? G0 : 0.f);
                cc2 = (d0 == 1) ? G1 : ((d0 == 2) ? G0 : 0.f);
                cc3 = (d0 == 2) ? G1 : 0.f;
            }
            St[ck_][ct][ct + 0] = f2bf(cc0);    // overwrites previous tile's band
            St[ck_][ct][ct + 1] = f2bf(cc1);
            St[ck_][ct][ct + 2] = f2bf(cc2);
            St[ck_][ct][ct + 3] = f2bf(cc3);
        }
        // rotate offs/mask; issue tile(it+2) loads (stay in flight across barriers)
        ofc = ofn; mvc = mvn;
        if (it + 2 < NTPB && tid < 96) {
            const int g = t0b + (it + 2) * TT + ct;
            ofn = 0.f; mvn = 0.f;
            if (g < LOUT) {
                ofn = offs[((size_t)b * LOUT + g) * 3 + ck_];
                mvn = mask[((size_t)b * 3 + ck_) * LOUT + g];
            }
        }
        LDS_BARRIER();   // St ready; also orders prev tile's GEMM2 xs-reads before G1 writes

        // ---- GEMM1 (per k): D[c][t] = x-window . S_k, K=64 ----
#pragma unroll
        for (int k = 0; k < 3; ++k) {
            floatx4 a1[2];
#pragma unroll
            for (int nf = 0; nf < 2; ++nf) {
                floatx4 z = {0.f, 0.f, 0.f, 0.f};
                a1[nf] = z;
            }
#pragma unroll
            for (int ks1 = 0; ks1 < 2; ++ks1) {
                const short8 a = ks1 ? axf1 : axf0;
                const short8 bfa = *(const short8*)
                    (&St[k][(lane & 15)][ks1 * 32 + acol8]);
                const short8 bfb = *(const short8*)
                    (&St[k][16 + (lane & 15)][ks1 * 32 + acol8]);
                a1[0] = __builtin_amdgcn_mfma_f32_16x16x32_bf16(a, bfa, a1[0], 0, 0, 0);
                a1[1] = __builtin_amdgcn_mfma_f32_16x16x32_bf16(a, bfb, a1[1], 0, 0, 0);
            }
            // D: col(t)=lane&15, row(c)=(lane>>4)*4+r -> xs[t][k*128+c], b64
#pragma unroll
            for (int nf = 0; nf < 2; ++nf) {
                const int tcol = nf * 16 + (lane & 15);
                const int cb   = wv * 16 + ((lane >> 4) << 2);
                uint2 q;
                q.x = pk(f2bf(a1[nf][0]), f2bf(a1[nf][1]));
                q.y = pk(f2bf(a1[nf][2]), f2bf(a1[nf][3]));
                *(uint2*)(&xs[tcol][k * 128 + cb]) = q;
            }
        }
        LDS_BARRIER();   // xs ready

        // ---- rotate x-window; issue chunk(it+3) load (hides under GEMM2) ----
        if (it + 1 < NTPB) {
            axf0 = axf1;
            axf1 = cvt8(xn0, xn1);              // chunk(it+2), issued a tile ago
            if (it + 3 <= NTPB) {               // only chunks 3,4 ever needed
                int tb = t0b + (it + 3) * 32 + acol8;
                if (tb > LL - 8) tb = LL - 8;
                xn0 = *(const floatx4*)(xrow + tb);
                xn1 = *(const floatx4*)(xrow + tb + 4);
            }
        }

        // ---- GEMM2: out[o][t], 12 k-steps, A from regs, B from LDS ----
        floatx4 acc[2];
#pragma unroll
        for (int nf = 0; nf < 2; ++nf) {
            floatx4 z = {0.f, 0.f, 0.f, 0.f};
            acc[nf] = z;
        }
#pragma unroll
        for (int ks = 0; ks < 12; ++ks) {
            const short8 bf0 = *(const short8*)(&xs[(lane & 15)][ks * 32 + acol8]);
            const short8 bf1 = *(const short8*)(&xs[16 + (lane & 15)][ks * 32 + acol8]);
            acc[0] = __builtin_amdgcn_mfma_f32_16x16x32_bf16(afr[ks], bf0, acc[0], 0, 0, 0);
            acc[1] = __builtin_amdgcn_mfma_f32_16x16x32_bf16(afr[ks], bf1, acc[1], 0, 0, 0);
        }

        // ---- epilogue: direct stores (measured clean: WRITE ~1.02x out) ----
#pragma unroll
        for (int r = 0; r < 4; ++r) {
            const int o = wv * 16 + ((lane >> 4) << 2) + r;
            float* orow = out + ((size_t)b * CO + o) * LOUT;
#pragma unroll
            for (int nf = 0; nf < 2; ++nf) {
                const int gt = t0 + nf * 16 + (lane & 15);
                if (gt < LOUT) orow[gt] = acc[nf][r] + bv[r];
            }
        }
    }
}

extern "C" void kernel_launch(void* const* d_in, const int* in_sizes, int n_in,
                              void* d_out, int out_size, void* d_ws, size_t ws_size,
                              hipStream_t stream) {
    const float* x    = (const float*)d_in[0];
    const float* offs = (const float*)d_in[1];
    const float* mask = (const float*)d_in[2];
    const float* w    = (const float*)d_in[3];
    const float* bias = (const float*)d_in[4];
    float* out = (float*)d_out;
    ushort* wbf2 = (ushort*)d_ws;            // 98.3 KB

    wcvt2_kernel<<<dim3(CO * CI / 256), dim3(256), 0, stream>>>(w, wbf2);
    dconv1d_pers_kernel<<<dim3(512), dim3(512), 0, stream>>>(
        x, offs, mask, wbf2, bias, out);
}

// Round 13
// 33.749 us; speedup vs baseline: 1.8133x; 1.0061x over previous
//
#include <hip/hip_runtime.h>

// Deformable Conv1d, two-stage MFMA + persistent 4-tile pipeline.
//   GEMM1 (per k): xs_k[c][t] = sum_tau x[c][t0+tau] * S_k[tau][t]  (banded S in LDS)
//   GEMM2:         out[o][t]  = sum_{ck'} w[o][ck'] * xs[ck'][t],  ck' = k*128+c
// R13: mf=2 LDS-read amortization. 4-wave blocks, wave owns 32 o/c rows;
//   afr[12][2] = 96 VGPR persistent (ALL indices compile-time -> registers;
//   R2's "spill" was a runtime-indexed ks loop, rule #20). Each B-fragment
//   ds_read_b128 now feeds 2 MFMAs -> block LDS reads halve (the ledger's
//   largest term, ~11.5 us/CU at R11's 8-way wave redundancy).
#define BB 16
#define CI 128
#define CO 128
#define LL 4096
#define LOUT 4094
#define CK 384            // GEMM2 K = 3*128
#define TT 32             // t per tile
#define NTPB 4            // tiles per block
#define STS 72            // S_k row stride (ushort)
#define XSS 408           // xs row stride (ushort)

// LDS-visibility barrier WITHOUT vmcnt(0) drain (keeps prefetches in flight)
#define LDS_BARRIER() do { \
    asm volatile("s_waitcnt lgkmcnt(0)" ::: "memory"); \
    __builtin_amdgcn_s_barrier(); \
} while (0)

typedef short short8 __attribute__((ext_vector_type(8)));
typedef float floatx4 __attribute__((ext_vector_type(4)));

__device__ __forceinline__ ushort f2bf(float f) {   // RNE f32 -> bf16
    union { float f; uint u; } v; v.f = f;
    uint r = v.u + 0x7FFFu + ((v.u >> 16) & 1u);
    return (ushort)(r >> 16);
}
__device__ __forceinline__ uint pk(ushort a, ushort b) {
    return (uint)a | ((uint)b << 16);
}
__device__ __forceinline__ short8 cvt8(floatx4 v0, floatx4 v1) {
    union { uint u[4]; short8 s; } r;
    r.u[0] = pk(f2bf(v0[0]), f2bf(v0[1]));
    r.u[1] = pk(f2bf(v0[2]), f2bf(v0[3]));
    r.u[2] = pk(f2bf(v1[0]), f2bf(v1[1]));
    r.u[3] = pk(f2bf(v1[2]), f2bf(v1[3]));
    return r.s;
}

// ---- w[o][c][k] f32 -> wbf2[o][k*128+c] bf16 ----
__global__ __launch_bounds__(256)
void wcvt2_kernel(const float* __restrict__ w, ushort* __restrict__ wbf2) {
    const int i = blockIdx.x * 256 + threadIdx.x;   // o*128 + c
    const int o = i >> 7, c = i & 127;
    const float w0 = w[i * 3 + 0], w1 = w[i * 3 + 1], w2 = w[i * 3 + 2];
    wbf2[o * CK +       c] = f2bf(w0);
    wbf2[o * CK + 128 + c] = f2bf(w1);
    wbf2[o * CK + 256 + c] = f2bf(w2);
}

__global__ __launch_bounds__(256, 2)
void dconv1d_mf2_kernel(const float* __restrict__ x,
                        const float* __restrict__ offs,
                        const float* __restrict__ mask,
                        const ushort* __restrict__ wbf2,
                        const float* __restrict__ bias,
                        float* __restrict__ out) {
    __shared__ ushort St[3][TT][STS];   // 13.5 KB sampling matrices
    __shared__ ushort xs[TT][XSS];      // 25.5 KB xs tile [t][k*128+c]

    const int tid  = threadIdx.x;
    const int lane = tid & 63;
    const int wv   = tid >> 6;          // 0..3; wave owns rows wv*32..wv*32+31
    const int bid  = blockIdx.x;
    // XCD-chunked swizzle over 512: XCD (bid&7) owns lb [k*64,(k+1)*64) -> 2 b's.
    const int lb   = (bid & 7) * 64 + (bid >> 3);
    const int b    = lb >> 5;
    const int t0b  = (lb & 31) * (TT * NTPB);   // 128-t stripe

    const int r15   = lane & 15;
    const int acol8 = (lane >> 4) << 3;         // k-dim subchunk

    // ---- prologue: issue ALL reusable/tile0+1 loads back-to-back ----
    short8 afr[12][2];                  // persistent GEMM2 A, 96 VGPR, static idx
#pragma unroll
    for (int ks = 0; ks < 12; ++ks)
#pragma unroll
        for (int mf = 0; mf < 2; ++mf)
            afr[ks][mf] = *(const short8*)
                (wbf2 + (size_t)(wv * 32 + mf * 16 + r15) * CK + ks * 32 + acol8);

    const float* xrow0 = x + ((size_t)b * CI + wv * 32 +      r15) * LL;
    const float* xrow1 = x + ((size_t)b * CI + wv * 32 + 16 + r15) * LL;
    floatx4 c0[2][2], c1[2][2], xn[2][2];       // chunks 0,1,2 raw f32
    {
        const int tb0 = t0b + acol8;            // chunks 0..3 never OOB
        const int tb1 = t0b + 32 + acol8;
        const int tb2 = t0b + 64 + acol8;
        c0[0][0] = *(const floatx4*)(xrow0 + tb0); c0[0][1] = *(const floatx4*)(xrow0 + tb0 + 4);
        c0[1][0] = *(const floatx4*)(xrow1 + tb0); c0[1][1] = *(const floatx4*)(xrow1 + tb0 + 4);
        c1[0][0] = *(const floatx4*)(xrow0 + tb1); c1[0][1] = *(const floatx4*)(xrow0 + tb1 + 4);
        c1[1][0] = *(const floatx4*)(xrow1 + tb1); c1[1][1] = *(const floatx4*)(xrow1 + tb1 + 4);
        xn[0][0] = *(const floatx4*)(xrow0 + tb2); xn[0][1] = *(const floatx4*)(xrow0 + tb2 + 4);
        xn[1][0] = *(const floatx4*)(xrow1 + tb2); xn[1][1] = *(const floatx4*)(xrow1 + tb2 + 4);
    }

    const int ct  = tid & 31;                   // coef unit t (tid<96)
    const int ck_ = (tid >> 5) < 3 ? (tid >> 5) : 0;
    float ofc = 0.f, mvc = 0.f, ofn = 0.f, mvn = 0.f;
    if (tid < 96) {
        const int g0 = t0b + ct;                // tile0 always < LOUT
        ofc = offs[((size_t)b * LOUT + g0) * 3 + ck_];
        mvc = mask[((size_t)b * 3 + ck_) * LOUT + g0];
        const int g1 = t0b + TT + ct;
        if (g1 < LOUT) {
            ofn = offs[((size_t)b * LOUT + g1) * 3 + ck_];
            mvn = mask[((size_t)b * 3 + ck_) * LOUT + g1];
        }
    }

    float bv[2][4];                             // bias for wave's 32 o-rows
#pragma unroll
    for (int mf = 0; mf < 2; ++mf)
#pragma unroll
        for (int r = 0; r < 4; ++r)
            bv[mf][r] = bias[wv * 32 + mf * 16 + ((lane >> 4) << 2) + r];

    // ---- zero St once (band positions tile-invariant) ----
    {
        uint* stz = (uint*)&St[0][0][0];
        for (int i = tid; i < 3 * TT * STS / 2; i += 256) stz[i] = 0;
    }

    short8 axf[2][2];                           // current x window (2 chunks x 2 mf)
#pragma unroll
    for (int mf = 0; mf < 2; ++mf) {
        axf[mf][0] = cvt8(c0[mf][0], c0[mf][1]);
        axf[mf][1] = cvt8(c1[mf][0], c1[mf][1]);
    }
    LDS_BARRIER();                              // St zero visible

#pragma unroll 1
    for (int it = 0; it < NTPB; ++it) {
        const int t0 = t0b + it * TT;

        // ---- coef -> St band (96 units; exact reference fp32 op order) ----
        if (tid < 96) {
            const int gt = t0 + ct;
            float cc0 = 0.f, cc1 = 0.f, cc2 = 0.f, cc3 = 0.f;
            if (gt < LOUT) {
                const float gtf = (float)gt;
                float T = (gtf + (float)ck_) + ofc;
                T = fminf(fmaxf(T, gtf), gtf + 2.0f);
                int U = (int)floorf(T);
                if (U > LL - 2) U = LL - 2;
                const float Uf = (float)U;
                const float G0 = fmaxf(0.f, 1.f - fabsf(Uf - T)) * mvc;
                const float G1 = fmaxf(0.f, 1.f - fabsf(Uf + 1.f - T)) * mvc;
                const int d0 = U - gt;
                cc0 = (d0 == 0) ? G0 : 0.f;
                cc1 = (d0 == 0) ? G1 : ((d0 == 1) ? G0 : 0.f);
                cc2 = (d0 == 1) ? G1 : ((d0 == 2) ? G0 : 0.f);
                cc3 = (d0 == 2) ? G1 : 0.f;
            }
            St[ck_][ct][ct + 0] = f2bf(cc0);    // overwrites previous tile's band
            St[ck_][ct][ct + 1] = f2bf(cc1);
            St[ck_][ct][ct + 2] = f2bf(cc2);
            St[ck_][ct][ct + 3] = f2bf(cc3);
        }
        // rotate offs/mask; issue tile(it+2) loads (stay in flight across barriers)
        ofc = ofn; mvc = mvn;
        if (it + 2 < NTPB && tid < 96) {
            const int g = t0b + (it + 2) * TT + ct;
            ofn = 0.f; mvn = 0.f;
            if (g < LOUT) {
                ofn = offs[((size_t)b * LOUT + g) * 3 + ck_];
                mvn = mask[((size_t)b * 3 + ck_) * LOUT + g];
            }
        }
        LDS_BARRIER();   // St ready; also orders prev tile's GEMM2 xs-reads

        // ---- GEMM1 (per k): D[c][t] = x-window . S_k, K=64, mf=2 ----
#pragma unroll
        for (int k = 0; k < 3; ++k) {
            floatx4 a1[2][2];
#pragma unroll
            for (int mf = 0; mf < 2; ++mf)
#pragma unroll
                for (int nf = 0; nf < 2; ++nf) {
                    floatx4 z = {0.f, 0.f, 0.f, 0.f};
                    a1[mf][nf] = z;
                }
#pragma unroll
            for (int ks1 = 0; ks1 < 2; ++ks1) {
                const short8 bfa = *(const short8*)(&St[k][r15][ks1 * 32 + acol8]);
                const short8 bfb = *(const short8*)(&St[k][16 + r15][ks1 * 32 + acol8]);
#pragma unroll
                for (int mf = 0; mf < 2; ++mf) {
                    a1[mf][0] = __builtin_amdgcn_mfma_f32_16x16x32_bf16(axf[mf][ks1], bfa, a1[mf][0], 0, 0, 0);
                    a1[mf][1] = __builtin_amdgcn_mfma_f32_16x16x32_bf16(axf[mf][ks1], bfb, a1[mf][1], 0, 0, 0);
                }
            }
            // D: col(t)=lane&15, row(c)=(lane>>4)*4+r -> xs[t][k*128+c], b64
#pragma unroll
            for (int mf = 0; mf < 2; ++mf)
#pragma unroll
                for (int nf = 0; nf < 2; ++nf) {
                    const int tcol = nf * 16 + r15;
                    const int cb   = wv * 32 + mf * 16 + ((lane >> 4) << 2);
                    uint2 q;
                    q.x = pk(f2bf(a1[mf][nf][0]), f2bf(a1[mf][nf][1]));
                    q.y = pk(f2bf(a1[mf][nf][2]), f2bf(a1[mf][nf][3]));
                    *(uint2*)(&xs[tcol][k * 128 + cb]) = q;
                }
        }
        LDS_BARRIER();   // xs ready

        // ---- rotate x-window; issue chunk(it+3) load (hides under GEMM2) ----
        if (it + 1 < NTPB) {
#pragma unroll
            for (int mf = 0; mf < 2; ++mf) {
                axf[mf][0] = axf[mf][1];
                axf[mf][1] = cvt8(xn[mf][0], xn[mf][1]);
            }
            if (it + 3 <= NTPB) {               // only chunks 3,4 ever needed
                int tb = t0b + (it + 3) * 32 + acol8;
                if (tb > LL - 8) tb = LL - 8;   // clamped lanes hit zero St rows
                xn[0][0] = *(const floatx4*)(xrow0 + tb);
                xn[0][1] = *(const floatx4*)(xrow0 + tb + 4);
                xn[1][0] = *(const floatx4*)(xrow1 + tb);
                xn[1][1] = *(const floatx4*)(xrow1 + tb + 4);
            }
        }

        // ---- GEMM2: out[o][t], 12 k-steps, A regs (mf=2), B reads amortized ----
        floatx4 acc[2][2];
#pragma unroll
        for (int mf = 0; mf < 2; ++mf)
#pragma unroll
            for (int nf = 0; nf < 2; ++nf) {
                floatx4 z = {0.f, 0.f, 0.f, 0.f};
                acc[mf][nf] = z;
            }
#pragma unroll
        for (int ks = 0; ks < 12; ++ks) {
            const short8 bf0 = *(const short8*)(&xs[r15][ks * 32 + acol8]);
            const short8 bf1 = *(const short8*)(&xs[16 + r15][ks * 32 + acol8]);
#pragma unroll
            for (int mf = 0; mf < 2; ++mf) {
                acc[mf][0] = __builtin_amdgcn_mfma_f32_16x16x32_bf16(afr[ks][mf], bf0, acc[mf][0], 0, 0, 0);
                acc[mf][1] = __builtin_amdgcn_mfma_f32_16x16x32_bf16(afr[ks][mf], bf1, acc[mf][1], 0, 0, 0);
            }
        }

        // ---- epilogue: direct stores (measured clean: WRITE ~1.02x out) ----
#pragma unroll
        for (int mf = 0; mf < 2; ++mf)
#pragma unroll
            for (int r = 0; r < 4; ++r) {
                const int o = wv * 32 + mf * 16 + ((lane >> 4) << 2) + r;
                float* orow = out + ((size_t)b * CO + o) * LOUT;
#pragma unroll
                for (int nf = 0; nf < 2; ++nf) {
                    const int gt = t0 + nf * 16 + r15;
                    if (gt < LOUT) orow[gt] = acc[mf][nf][r] + bv[mf][r];
                }
            }
    }
}

extern "C" void kernel_launch(void* const* d_in, const int* in_sizes, int n_in,
                              void* d_out, int out_size, void* d_ws, size_t ws_size,
                              hipStream_t stream) {
    const float* x    = (const float*)d_in[0];
    const float* offs = (const float*)d_in[1];
    const float* mask = (const float*)d_in[2];
    const float* w    = (const float*)d_in[3];
    const float* bias = (const float*)d_in[4];
    float* out = (float*)d_out;
    ushort* wbf2 = (ushort*)d_ws;            // 98.3 KB

    wcvt2_kernel<<<dim3(CO * CI / 256), dim3(256), 0, stream>>>(w, wbf2);
    dconv1d_mf2_kernel<<<dim3(512), dim3(256), 0, stream>>>(
        x, offs, mask, wbf2, bias, out);
}